// Round 8
// baseline (162.013 us; speedup 1.0000x reference)
//
#include <hip/hip_runtime.h>
#include <math.h>

#define B_DIM 256
#define M_DIM 4096
#define EPSV 1e-7f
#define THREADS 1024
#define CHUNK 1024
#define CHUNK_F4 (CHUNK * 9 / 4)   // 2304 float4 per array per chunk
#define NCHUNK (M_DIM / CHUNK)     // 4
#define ROW_F4 (M_DIM * 9 / 4)     // 9216
#define RECON_F4_PER_BLOCK ((B_DIM * 128 * 128 / 4) / B_DIM)  // 4096
#define TAIL (CHUNK_F4 - 2 * THREADS)   // 256: threads 0..255 carry a 3rd float4

// ws layout (floats):
//   [0 .. 2048)  per-block partials: 256 blocks x 8 {coord,width,val,nval,cont,recon}

__global__ __launch_bounds__(THREADS, 4) void fused_loss_kernel(
    const float4* __restrict__ pred4, const float4* __restrict__ tgt4,
    const float4* __restrict__ rec4, const float4* __restrict__ img4,
    float* __restrict__ blk_out)
{
    __shared__ float s_pred[CHUNK * 9];                // 36 KB stage
    __shared__ float s_tgt[CHUNK * 9];                 // 36 KB stage
    __shared__ float s_p4[M_DIM];                      // 16 KB
    __shared__ float s_p5[M_DIM];                      // 16 KB
    __shared__ unsigned long long s_words[M_DIM / 64]; // 512 B
    __shared__ float s_red[16][6];

    const int b    = blockIdx.x;
    const int t    = threadIdx.x;
    const int lane = t & 63;
    const int wave = t >> 6;

    const float4* pb = pred4 + (size_t)b * ROW_F4;
    const float4* tb = tgt4  + (size_t)b * ROW_F4;

    float4 Pa[3], Ta[3], Pb[3], Tb[3];

    // issue chunk-0 loads first; recon compute below overlaps their stream-in
    {
        const float4* pc = pb;  const float4* tc = tb;
        Pa[0] = pc[t];          Ta[0] = tc[t];
        Pa[1] = pc[t + 1024];   Ta[1] = tc[t + 1024];
        if (t < TAIL) { Pa[2] = pc[t + 2048]; Ta[2] = tc[t + 2048]; }
    }

    // ---- reconstruction MSE: this block's contiguous 1/256 slice ----
    float recon_s = 0.f;
    {
        const float4* rb = rec4 + (size_t)b * RECON_F4_PER_BLOCK;
        const float4* ib = img4 + (size_t)b * RECON_F4_PER_BLOCK;
        #pragma unroll
        for (int i = 0; i < RECON_F4_PER_BLOCK / THREADS; ++i) {   // 4 iters
            int idx = i * THREADS + t;
            float4 r = rb[idx]; float4 m = ib[idx];
            float d0 = r.x - m.x, d1 = r.y - m.y, d2 = r.z - m.z, d3 = r.w - m.w;
            recon_s += d0 * d0 + d1 * d1 + d2 * d2 + d3 * d3;
        }
    }

    float coord_s = 0.f, width_s = 0.f, val_s = 0.f, nval_s = 0.f;

    #pragma unroll
    for (int c = 0; c < NCHUNK; ++c) {
        if (c) __syncthreads();   // stage buffer fully consumed by all waves

        // ---- write prefetched chunk c from registers to LDS stage ----
        {
            float4* P = (c & 1) ? Pb : Pa;
            float4* T = (c & 1) ? Tb : Ta;
            ((float4*)s_pred)[t]        = P[0];
            ((float4*)s_tgt)[t]         = T[0];
            ((float4*)s_pred)[t + 1024] = P[1];
            ((float4*)s_tgt)[t + 1024]  = T[1];
            if (t < TAIL) {
                ((float4*)s_pred)[t + 2048] = P[2];
                ((float4*)s_tgt)[t + 2048]  = T[2];
            }
        }
        __syncthreads();

        // ---- issue chunk c+1 loads; they stream while we consume chunk c ----
        if (c < NCHUNK - 1) {
            const float4* pc = pb + (c + 1) * CHUNK_F4;
            const float4* tc = tb + (c + 1) * CHUNK_F4;
            float4* P = (c & 1) ? Pa : Pb;
            float4* T = (c & 1) ? Ta : Tb;
            P[0] = pc[t];          T[0] = tc[t];
            P[1] = pc[t + 1024];   T[1] = tc[t + 1024];
            if (t < TAIL) { P[2] = pc[t + 2048]; T[2] = tc[t + 2048]; }
        }

        // ---- consume: thread t owns element (c*1024 + t) entirely ----
        const float* pe = s_pred + t * 9;   // stride 9 coprime to 32 banks
        const float* te = s_tgt  + t * 9;
        float p0 = pe[0], p1 = pe[1], p2 = pe[2], p3 = pe[3], p4 = pe[4],
              p5 = pe[5], p6 = pe[6], p7 = pe[7], p8 = pe[8];
        float t0 = te[0], t1 = te[1], t2 = te[2], t3 = te[3], t4 = te[4],
              t5 = te[5], t6 = te[6], t7 = te[7], t8 = te[8];

        bool valid = (t8 > 0.5f);
        float fm = valid ? 1.f : 0.f;
        coord_s += fm * (fabsf(p0 - t0) + fabsf(p1 - t1) + fabsf(p2 - t2) +
                         fabsf(p3 - t3) + fabsf(p4 - t4) + fabsf(p5 - t5));
        width_s += fm * (fabsf(p6 - t6) + fabsf(p7 - t7));
        nval_s  += fm;

        float pc8 = fminf(fmaxf(p8, EPSV), 1.0f - EPSV);
        val_s += -(t8 * __logf(pc8) + (1.0f - t8) * __logf(1.0f - pc8));

        const int m = c * CHUNK + t;
        s_p4[m] = p4;
        s_p5[m] = p5;
        unsigned long long bal = __ballot(valid);
        if (lane == 0) s_words[c * 16 + wave] = bal;
    }
    __syncthreads();

    // ---- continuity: next-valid bit-scan over full row ----
    float cont_s = 0.f;
    #pragma unroll
    for (int p = 0; p < 4; ++p) {
        const int m   = p * 1024 + t;
        const int w   = m >> 6;
        const int bit = m & 63;
        unsigned long long wv = s_words[w];
        if ((wv >> bit) & 1ULL) {
            unsigned long long mask = wv & ((bit == 63) ? 0ULL : (~0ULL << (bit + 1)));
            int nxt = -1;
            if (mask) {
                nxt = (w << 6) + __builtin_ctzll(mask);
            } else {
                for (int w2 = w + 1; w2 < (M_DIM / 64); ++w2) {
                    unsigned long long mw = s_words[w2];
                    if (mw) { nxt = (w2 << 6) + __builtin_ctzll(mw); break; }
                }
            }
            if (nxt >= 0) {
                cont_s += 0.5f * (fabsf(s_p4[m] - s_p4[nxt]) +
                                  fabsf(s_p5[m] - s_p5[nxt]));
            }
        }
    }

    // ---- block reduction of 6 partials; per-block slot write (no atomics) ----
    float vals[6] = {coord_s, width_s, val_s, nval_s, cont_s, recon_s};
    #pragma unroll
    for (int i = 0; i < 6; ++i) {
        float v = vals[i];
        #pragma unroll
        for (int off = 32; off > 0; off >>= 1) v += __shfl_down(v, off, 64);
        vals[i] = v;
    }
    if (lane == 0) {
        #pragma unroll
        for (int i = 0; i < 6; ++i) s_red[wave][i] = vals[i];
    }
    __syncthreads();
    if (t == 0) {
        float acc[6] = {0.f, 0.f, 0.f, 0.f, 0.f, 0.f};
        for (int wv = 0; wv < 16; ++wv)
            #pragma unroll
            for (int i = 0; i < 6; ++i) acc[i] += s_red[wv][i];
        float* r = blk_out + b * 8;
        #pragma unroll
        for (int i = 0; i < 6; ++i) r[i] = acc[i];
    }
}

__global__ __launch_bounds__(256) void finalize_kernel(
    const float* __restrict__ ws, float* __restrict__ out)
{
    const int t = threadIdx.x;
    const float* rb = ws + t * 8;
    float v[6];
    #pragma unroll
    for (int i = 0; i < 6; ++i) v[i] = rb[i];

    __shared__ float sred[4][6];
    int lane = t & 63, wave = t >> 6;
    #pragma unroll
    for (int i = 0; i < 6; ++i) {
        float x = v[i];
        #pragma unroll
        for (int off = 32; off > 0; off >>= 1) x += __shfl_down(x, off, 64);
        v[i] = x;
    }
    if (lane == 0)
        #pragma unroll
        for (int i = 0; i < 6; ++i) sred[wave][i] = v[i];
    __syncthreads();
    if (t == 0) {
        double a[6];
        #pragma unroll
        for (int i = 0; i < 6; ++i)
            a[i] = (double)sred[0][i] + (double)sred[1][i] +
                   (double)sred[2][i] + (double)sred[3][i];
        double coord_num = a[0], width_num = a[1], val_sum = a[2],
               nv = a[3], cont = a[4], recon = a[5];

        double coord = (nv > 0.0) ? coord_num / fmax(nv * 6.0, 1.0) : 0.0;
        double width = (nv > 0.0) ? width_num / fmax(nv * 2.0, 1.0) : 0.0;
        double validity = val_sum / ((double)B_DIM * (double)M_DIM);
        double contl    = cont / (double)B_DIM;
        double reconl   = recon / ((double)B_DIM * 128.0 * 128.0);

        out[0] = (float)(coord + width + 2.0 * validity +
                         0.2 * contl + 0.1 * reconl);
    }
}

extern "C" void kernel_launch(void* const* d_in, const int* in_sizes, int n_in,
                              void* d_out, int out_size, void* d_ws, size_t ws_size,
                              hipStream_t stream) {
    const float* pred = (const float*)d_in[0];
    const float* tgt  = (const float*)d_in[1];
    const float* rec  = (const float*)d_in[2];
    const float* img  = (const float*)d_in[3];
    float* ws = (float*)d_ws;

    fused_loss_kernel<<<B_DIM, THREADS, 0, stream>>>(
        (const float4*)pred, (const float4*)tgt,
        (const float4*)rec, (const float4*)img, ws);
    finalize_kernel<<<1, 256, 0, stream>>>(ws, (float*)d_out);
}

// Round 9
// 131.934 us; speedup vs baseline: 1.2280x; 1.2280x over previous
//
#include <hip/hip_runtime.h>
#include <math.h>

#define B_DIM 256
#define M_DIM 4096
#define EPSV 1e-7f
#define THREADS 1024
#define CHUNK 1024
#define CHUNK_F4 (CHUNK * 9 / 4)   // 2304 float4 per array per chunk
#define NCHUNK (M_DIM / CHUNK)     // 4
#define ROW_F4 (M_DIM * 9 / 4)     // 9216
#define RECON_F4_PER_BLOCK ((B_DIM * 128 * 128 / 4) / B_DIM)  // 4096
#define TAIL (CHUNK_F4 - 2 * THREADS)   // 256: threads 0..255 carry a 3rd float4

// ws layout (floats):
//   [0 .. 2048)  per-block partials: 256 blocks x 8 {coord,width,val,nval,cont,recon}

// Named-register prefetch macros — NOTHING addressable, so no scratch.
#define LOADC(cc, P0, P1, P2, T0, T1, T2)                      \
    do {                                                       \
        const float4* pc_ = pb + (cc) * CHUNK_F4;              \
        const float4* tc_ = tb + (cc) * CHUNK_F4;              \
        P0 = pc_[t];        T0 = tc_[t];                       \
        P1 = pc_[t + 1024]; T1 = tc_[t + 1024];                \
        if (t < TAIL) { P2 = pc_[t + 2048]; T2 = tc_[t + 2048]; } \
    } while (0)

#define STOREC(P0, P1, P2, T0, T1, T2)                         \
    do {                                                       \
        ((float4*)s_pred)[t]        = P0;                      \
        ((float4*)s_tgt)[t]         = T0;                      \
        ((float4*)s_pred)[t + 1024] = P1;                      \
        ((float4*)s_tgt)[t + 1024]  = T1;                      \
        if (t < TAIL) {                                        \
            ((float4*)s_pred)[t + 2048] = P2;                  \
            ((float4*)s_tgt)[t + 2048]  = T2;                  \
        }                                                      \
    } while (0)

__global__ void __launch_bounds__(THREADS)
__attribute__((amdgpu_waves_per_eu(4, 4)))
fused_loss_kernel(
    const float4* __restrict__ pred4, const float4* __restrict__ tgt4,
    const float4* __restrict__ rec4, const float4* __restrict__ img4,
    float* __restrict__ blk_out)
{
    __shared__ float s_pred[CHUNK * 9];                // 36 KB stage
    __shared__ float s_tgt[CHUNK * 9];                 // 36 KB stage
    __shared__ float s_p4[M_DIM];                      // 16 KB
    __shared__ float s_p5[M_DIM];                      // 16 KB
    __shared__ unsigned long long s_words[M_DIM / 64]; // 512 B
    __shared__ float s_red[16][6];

    const int b    = blockIdx.x;
    const int t    = threadIdx.x;
    const int lane = t & 63;
    const int wave = t >> 6;

    const float4* pb = pred4 + (size_t)b * ROW_F4;
    const float4* tb = tgt4  + (size_t)b * ROW_F4;

    float coord_s = 0.f, width_s = 0.f, val_s = 0.f, nval_s = 0.f;

    // consume chunk c from the LDS stage; thread t owns element c*1024+t
    auto consume = [&](int c) {
        const float* pe = s_pred + t * 9;   // stride 9 coprime to 32 banks
        const float* te = s_tgt  + t * 9;
        float p0 = pe[0], p1 = pe[1], p2 = pe[2], p3 = pe[3], p4 = pe[4],
              p5 = pe[5], p6 = pe[6], p7 = pe[7], p8 = pe[8];
        float t0 = te[0], t1 = te[1], t2 = te[2], t3 = te[3], t4 = te[4],
              t5 = te[5], t6 = te[6], t7 = te[7], t8 = te[8];

        bool valid = (t8 > 0.5f);
        float fm = valid ? 1.f : 0.f;
        coord_s += fm * (fabsf(p0 - t0) + fabsf(p1 - t1) + fabsf(p2 - t2) +
                         fabsf(p3 - t3) + fabsf(p4 - t4) + fabsf(p5 - t5));
        width_s += fm * (fabsf(p6 - t6) + fabsf(p7 - t7));
        nval_s  += fm;

        float pc8 = fminf(fmaxf(p8, EPSV), 1.0f - EPSV);
        val_s += -(t8 * __logf(pc8) + (1.0f - t8) * __logf(1.0f - pc8));

        const int m = c * CHUNK + t;
        s_p4[m] = p4;
        s_p5[m] = p5;
        unsigned long long bal = __ballot(valid);
        if (lane == 0) s_words[c * 16 + wave] = bal;
    };

    float4 PA0, PA1, PA2, TA0, TA1, TA2;
    float4 PB0, PB1, PB2, TB0, TB1, TB2;

    // chunk-0 loads in flight while recon computes
    LOADC(0, PA0, PA1, PA2, TA0, TA1, TA2);

    // ---- reconstruction MSE: this block's contiguous 1/256 slice ----
    float recon_s = 0.f;
    {
        const float4* rb = rec4 + (size_t)b * RECON_F4_PER_BLOCK;
        const float4* ib = img4 + (size_t)b * RECON_F4_PER_BLOCK;
        #pragma unroll
        for (int i = 0; i < RECON_F4_PER_BLOCK / THREADS; ++i) {   // 4 iters
            int idx = i * THREADS + t;
            float4 r = rb[idx]; float4 m = ib[idx];
            float d0 = r.x - m.x, d1 = r.y - m.y, d2 = r.z - m.z, d3 = r.w - m.w;
            recon_s += d0 * d0 + d1 * d1 + d2 * d2 + d3 * d3;
        }
    }

    // ---- hand-written 4-stage pipeline: loads for c+1 stream during consume(c) ----
    STOREC(PA0, PA1, PA2, TA0, TA1, TA2);
    __syncthreads();
    LOADC(1, PB0, PB1, PB2, TB0, TB1, TB2);
    consume(0);

    __syncthreads();
    STOREC(PB0, PB1, PB2, TB0, TB1, TB2);
    __syncthreads();
    LOADC(2, PA0, PA1, PA2, TA0, TA1, TA2);
    consume(1);

    __syncthreads();
    STOREC(PA0, PA1, PA2, TA0, TA1, TA2);
    __syncthreads();
    LOADC(3, PB0, PB1, PB2, TB0, TB1, TB2);
    consume(2);

    __syncthreads();
    STOREC(PB0, PB1, PB2, TB0, TB1, TB2);
    __syncthreads();
    consume(3);

    __syncthreads();

    // ---- continuity: next-valid bit-scan over full row ----
    float cont_s = 0.f;
    #pragma unroll
    for (int p = 0; p < 4; ++p) {
        const int m   = p * 1024 + t;
        const int w   = m >> 6;
        const int bit = m & 63;
        unsigned long long wv = s_words[w];
        if ((wv >> bit) & 1ULL) {
            unsigned long long mask = wv & ((bit == 63) ? 0ULL : (~0ULL << (bit + 1)));
            int nxt = -1;
            if (mask) {
                nxt = (w << 6) + __builtin_ctzll(mask);
            } else {
                for (int w2 = w + 1; w2 < (M_DIM / 64); ++w2) {
                    unsigned long long mw = s_words[w2];
                    if (mw) { nxt = (w2 << 6) + __builtin_ctzll(mw); break; }
                }
            }
            if (nxt >= 0) {
                cont_s += 0.5f * (fabsf(s_p4[m] - s_p4[nxt]) +
                                  fabsf(s_p5[m] - s_p5[nxt]));
            }
        }
    }

    // ---- block reduction of 6 partials; per-block slot write (no atomics) ----
    float vals[6] = {coord_s, width_s, val_s, nval_s, cont_s, recon_s};
    #pragma unroll
    for (int i = 0; i < 6; ++i) {
        float v = vals[i];
        #pragma unroll
        for (int off = 32; off > 0; off >>= 1) v += __shfl_down(v, off, 64);
        vals[i] = v;
    }
    if (lane == 0) {
        #pragma unroll
        for (int i = 0; i < 6; ++i) s_red[wave][i] = vals[i];
    }
    __syncthreads();
    if (t == 0) {
        float acc[6] = {0.f, 0.f, 0.f, 0.f, 0.f, 0.f};
        for (int wv = 0; wv < 16; ++wv)
            #pragma unroll
            for (int i = 0; i < 6; ++i) acc[i] += s_red[wv][i];
        float* r = blk_out + b * 8;
        #pragma unroll
        for (int i = 0; i < 6; ++i) r[i] = acc[i];
    }
}

__global__ __launch_bounds__(256) void finalize_kernel(
    const float* __restrict__ ws, float* __restrict__ out)
{
    const int t = threadIdx.x;
    const float* rb = ws + t * 8;
    float v[6];
    #pragma unroll
    for (int i = 0; i < 6; ++i) v[i] = rb[i];

    __shared__ float sred[4][6];
    int lane = t & 63, wave = t >> 6;
    #pragma unroll
    for (int i = 0; i < 6; ++i) {
        float x = v[i];
        #pragma unroll
        for (int off = 32; off > 0; off >>= 1) x += __shfl_down(x, off, 64);
        v[i] = x;
    }
    if (lane == 0)
        #pragma unroll
        for (int i = 0; i < 6; ++i) sred[wave][i] = v[i];
    __syncthreads();
    if (t == 0) {
        double a[6];
        #pragma unroll
        for (int i = 0; i < 6; ++i)
            a[i] = (double)sred[0][i] + (double)sred[1][i] +
                   (double)sred[2][i] + (double)sred[3][i];
        double coord_num = a[0], width_num = a[1], val_sum = a[2],
               nv = a[3], cont = a[4], recon = a[5];

        double coord = (nv > 0.0) ? coord_num / fmax(nv * 6.0, 1.0) : 0.0;
        double width = (nv > 0.0) ? width_num / fmax(nv * 2.0, 1.0) : 0.0;
        double validity = val_sum / ((double)B_DIM * (double)M_DIM);
        double contl    = cont / (double)B_DIM;
        double reconl   = recon / ((double)B_DIM * 128.0 * 128.0);

        out[0] = (float)(coord + width + 2.0 * validity +
                         0.2 * contl + 0.1 * reconl);
    }
}

extern "C" void kernel_launch(void* const* d_in, const int* in_sizes, int n_in,
                              void* d_out, int out_size, void* d_ws, size_t ws_size,
                              hipStream_t stream) {
    const float* pred = (const float*)d_in[0];
    const float* tgt  = (const float*)d_in[1];
    const float* rec  = (const float*)d_in[2];
    const float* img  = (const float*)d_in[3];
    float* ws = (float*)d_ws;

    fused_loss_kernel<<<B_DIM, THREADS, 0, stream>>>(
        (const float4*)pred, (const float4*)tgt,
        (const float4*)rec, (const float4*)img, ws);
    finalize_kernel<<<1, 256, 0, stream>>>(ws, (float*)d_out);
}